// Round 13
// baseline (215.698 us; speedup 1.0000x reference)
//
#include <hip/hip_runtime.h>

#define DIM 8192
#define BATCH 256
#define BN 256
#define BK 32
#define KSPLIT 8
#define KLEN (DIM / KSPLIT)   // 1024 k per block
#define NSTEP (KLEN / BK)     // 32 steps
#define NTILE (DIM / BN)      // 32 n-tiles
#define LDSBUF 49152          // per-buffer: A 16 KB (bf16) + B 32 KB (f32)

typedef __attribute__((ext_vector_type(8))) short   short8;   // 8 bf16 frag
typedef __attribute__((ext_vector_type(4))) float   f32x4;
typedef __attribute__((ext_vector_type(4))) unsigned short u16x4;
typedef __attribute__((ext_vector_type(8))) unsigned short u16x8;

__device__ __forceinline__ unsigned short f2b(float f) {
    unsigned u = __builtin_bit_cast(unsigned, f);
    u = (u + 0x7FFFu + ((u >> 16) & 1u)) >> 16;
    return (unsigned short)u;
}
__device__ __forceinline__ float b2f(unsigned short h) {
    unsigned u = ((unsigned)h) << 16;
    return __builtin_bit_cast(float, u);
}

// ---- prepass: x f32 -> bf16 (ws+0, 4 MB); also zero the split-K tickets ----
__global__ __launch_bounds__(512) void cvt_x_kernel(const float* __restrict__ x,
                                                    unsigned short* __restrict__ xb,
                                                    unsigned int* __restrict__ tickets) {
    int i = blockIdx.x * 512 + threadIdx.x;
    if (blockIdx.x == 0 && threadIdx.x < NTILE) tickets[threadIdx.x] = 0u;
    f32x4 v = reinterpret_cast<const f32x4*>(x)[i];
    u16x4 o;
    o[0] = f2b(v[0]); o[1] = f2b(v[1]); o[2] = f2b(v[2]); o[3] = f2b(v[3]);
    reinterpret_cast<u16x4*>(xb)[i] = o;
}

// ---- GEMM + fused split-K reduce ----
// 256 blocks = 32 nt x 8 ks (ks = bid&7 -> one ks per XCD; 512 KB xb slab per
// L2). 512 thr (8 waves); BM=256 (U read exactly once), BN=256. All staging
// via global_load_lds into frag-linear LDS (lane-exact source addressing,
// conflict-free by construction). 3 buffers, distance-2, one counted vmcnt(6)
// + raw s_barrier per step (R12-proven body, byte-identical).
// Epilogue: store bf16 partial, ticket via device-scope atomicAdd; the 8th
// block for an nt reduces all 8 partials (fixed ks order -> deterministic)
// and writes the f32 output slice. No separate reduce kernel.
__global__ __launch_bounds__(512) void gemm_kernel(const unsigned short* __restrict__ xb,
                                                   const float* __restrict__ U,
                                                   unsigned short* __restrict__ part,
                                                   unsigned int* __restrict__ tickets,
                                                   float* __restrict__ out) {
    __shared__ unsigned char lds[3][LDSBUF];
    __shared__ int isLast;

    const int tid  = threadIdx.x;
    const int lane = tid & 63;
    const int w    = tid >> 6;

    const int bid = blockIdx.x;
    const int ks  = bid & 7;
    const int nt  = bid >> 3;
    const int n0  = nt * BN;
    const int kb  = ks * KLEN;

    // --- staging chunks: c = 6w+j. c<16: A-frag c (16 batch rows x 32 k bf16).
    // c>=16: cc=c-16: B-piece (nfg=cc>>1, q=cc&1): 16 U-rows x 4-of-8 k (f32).
    const char* sbase[6];
    int soff[6], sstr[6];
#pragma unroll
    for (int j = 0; j < 6; ++j) {
        const int c = 6 * w + j;
        if (c < 16) {
            sbase[j] = (const char*)(xb + (long)(16 * c + (lane & 15)) * DIM
                                        + kb + (lane >> 4) * 8);
            soff[j] = c * 1024;
            sstr[j] = BK * 2;
        } else {
            const int cc = c - 16, nfg = cc >> 1, q = cc & 1;
            sbase[j] = (const char*)(U + (long)(n0 + 16 * nfg + (lane & 15)) * DIM
                                       + kb + (lane >> 4) * 8 + q * 4);
            soff[j] = 16384 + cc * 1024;
            sstr[j] = BK * 4;
        }
    }

#define STAGE(TS, BUF)                                                               \
    do {                                                                             \
        _Pragma("unroll")                                                            \
        for (int j = 0; j < 6; ++j)                                                  \
            __builtin_amdgcn_global_load_lds(                                        \
                (const __attribute__((address_space(1))) void*)(sbase[j] + (long)(TS) * sstr[j]), \
                (__attribute__((address_space(3))) void*)&lds[BUF][soff[j] + lane * 16],          \
                16, 0, 0);                                                           \
    } while (0)

    f32x4 acc[16][2];
#pragma unroll
    for (int a = 0; a < 16; ++a) {
        acc[a][0] = (f32x4){0.f, 0.f, 0.f, 0.f};
        acc[a][1] = (f32x4){0.f, 0.f, 0.f, 0.f};
    }

    // ---- prologue: fill bufs 0,1; retire stage(0)
    STAGE(0, 0);
    STAGE(1, 1);
    asm volatile("s_waitcnt vmcnt(6)" ::: "memory");
    __builtin_amdgcn_s_barrier();
    asm volatile("" ::: "memory");

    for (int t = 0; t < NSTEP; ++t) {
        const int buf = t % 3;
        const int ts  = (t + 2 < NSTEP) ? t + 2 : NSTEP - 1;
        STAGE(ts, (t + 2) % 3);
        __builtin_amdgcn_sched_barrier(0);

        const char* La = (const char*)&lds[buf][0];
        const char* Lb = (const char*)&lds[buf][16384];

        // B frags for this wave's 2 col-groups: f32 LDS -> bf16 regs
        short8 Bf[2];
#pragma unroll
        for (int nf = 0; nf < 2; ++nf) {
            const int nfg = 2 * w + nf;
            f32x4 q0 = *(const f32x4*)(Lb + (nfg * 2 + 0) * 1024 + lane * 16);
            f32x4 q1 = *(const f32x4*)(Lb + (nfg * 2 + 1) * 1024 + lane * 16);
#pragma unroll
            for (int jj = 0; jj < 4; ++jj) {
                Bf[nf][jj]     = (short)f2b(q0[jj]);
                Bf[nf][jj + 4] = (short)f2b(q1[jj]);
            }
        }
        __builtin_amdgcn_s_setprio(1);
#pragma unroll
        for (int a = 0; a < 16; ++a) {
            short8 Af = *(const short8*)(La + a * 1024 + lane * 16);
            acc[a][0] = __builtin_amdgcn_mfma_f32_16x16x32_bf16(Af, Bf[0], acc[a][0], 0, 0, 0);
            acc[a][1] = __builtin_amdgcn_mfma_f32_16x16x32_bf16(Af, Bf[1], acc[a][1], 0, 0, 0);
        }
        __builtin_amdgcn_s_setprio(0);

        // retire stage(t+1) (keep stage(t+2)'s 6 in flight); next buf ready
        asm volatile("s_waitcnt vmcnt(6)" ::: "memory");
        __builtin_amdgcn_s_barrier();
        asm volatile("" ::: "memory");
    }
#undef STAGE

    // ---- partial store (bf16): D row=(l>>4)*4+rr -> batch, col=l&15
    unsigned short* p = part + (long)ks * (BATCH * DIM);
    const int pcol = n0 + 32 * w + (lane & 15);
#pragma unroll
    for (int a = 0; a < 16; ++a) {
        const int prow = 16 * a + (lane >> 4) * 4;
#pragma unroll
        for (int nf = 0; nf < 2; ++nf) {
#pragma unroll
            for (int rr = 0; rr < 4; ++rr)
                p[(long)(prow + rr) * DIM + pcol + nf * 16] = f2b(acc[a][nf][rr]);
        }
    }

    // ---- split-K ticket: last block for this nt reduces and writes out ----
    __threadfence();          // make this block's partial visible device-wide
    __syncthreads();          // all threads' stores + fences done
    if (tid == 0) {
        unsigned old = atomicAdd(&tickets[nt], 1u);
        isLast = (old == KSPLIT - 1) ? 1 : 0;
    }
    __syncthreads();
    if (isLast) {
        __threadfence();      // acquire: other blocks' partials now visible
        // reduce nt's slice: 256 batch x 256 cols; 512 thr x 16 u16x8 each.
        const long stride8 = (long)BATCH * DIM / 8;   // u16x8 per partial
        const u16x8* pv = reinterpret_cast<const u16x8*>(part);
#pragma unroll
        for (int kk = 0; kk < 16; ++kk) {
            const int v   = tid + 512 * kk;        // 0..8191
            const int b   = v >> 5;                // batch row
            const int c8  = v & 31;                // col-group of 8
            const long idx = (long)b * (DIM / 8) + (n0 / 8) + c8;
            float s[8];
#pragma unroll
            for (int j = 0; j < 8; ++j) s[j] = 0.f;
#pragma unroll
            for (int k2 = 0; k2 < KSPLIT; ++k2) {
                u16x8 pvv = pv[k2 * stride8 + idx];
#pragma unroll
                for (int j = 0; j < 8; ++j) s[j] += b2f(pvv[j]);
            }
            f32x4 o0 = {s[0], s[1], s[2], s[3]};
            f32x4 o1 = {s[4], s[5], s[6], s[7]};
            float* ob = out + (long)b * DIM + n0 + c8 * 8;
            *reinterpret_cast<f32x4*>(ob)     = o0;
            *reinterpret_cast<f32x4*>(ob + 4) = o1;
        }
    }
}

extern "C" void kernel_launch(void* const* d_in, const int* in_sizes, int n_in,
                              void* d_out, int out_size, void* d_ws, size_t ws_size,
                              hipStream_t stream) {
    const float* x = (const float*)d_in[0];     // [256, 8192] f32
    const float* U = (const float*)d_in[1];     // [8192, 8192] f32
    float* outp = (float*)d_out;                // [256, 8192] f32

    unsigned short* xb   = (unsigned short*)d_ws;                                    // 4 MB
    unsigned short* part = (unsigned short*)((char*)d_ws + (size_t)BATCH * DIM * 2); // 32 MB bf16
    unsigned int* tickets = (unsigned int*)((char*)d_ws + (size_t)BATCH * DIM * 2
                                            + (size_t)KSPLIT * BATCH * DIM * 2);     // 128 B

    cvt_x_kernel<<<(BATCH * DIM / 4) / 512, 512, 0, stream>>>(x, xb, tickets);
    gemm_kernel<<<NTILE * KSPLIT, 512, 0, stream>>>(xb, U, part, tickets, outp);
}

// Round 14
// 92.896 us; speedup vs baseline: 2.3219x; 2.3219x over previous
//
#include <hip/hip_runtime.h>

#define DIM 8192
#define BATCH 256
#define BN 256
#define BK 32
#define KSPLIT 8
#define KLEN (DIM / KSPLIT)   // 1024 k per block
#define NSTEP (KLEN / BK)     // 32 steps
#define NTILE (DIM / BN)      // 32 n-tiles
#define LDSBUF 49152          // per-buffer: A 16 KB (bf16) + B 32 KB (f32)

typedef __attribute__((ext_vector_type(8))) short   short8;   // 8 bf16 frag
typedef __attribute__((ext_vector_type(4))) float   f32x4;
typedef __attribute__((ext_vector_type(4))) unsigned short u16x4;
typedef __attribute__((ext_vector_type(8))) unsigned short u16x8;

__device__ __forceinline__ unsigned short f2b(float f) {
    unsigned u = __builtin_bit_cast(unsigned, f);
    u = (u + 0x7FFFu + ((u >> 16) & 1u)) >> 16;
    return (unsigned short)u;
}
__device__ __forceinline__ float b2f(unsigned short h) {
    unsigned u = ((unsigned)h) << 16;
    return __builtin_bit_cast(float, u);
}

// ---- prepass: x f32 -> bf16 (ws+0, 4 MB) ----
__global__ __launch_bounds__(512) void cvt_x_kernel(const float* __restrict__ x,
                                                    unsigned short* __restrict__ xb) {
    int i = blockIdx.x * 512 + threadIdx.x;
    f32x4 v = reinterpret_cast<const f32x4*>(x)[i];
    u16x4 o;
    o[0] = f2b(v[0]); o[1] = f2b(v[1]); o[2] = f2b(v[2]); o[3] = f2b(v[3]);
    reinterpret_cast<u16x4*>(xb)[i] = o;
}

// ---- GEMM partials (bf16): p[ks][b][i] = sum_{j in ks-eighth} U[i,j]*x[b,j]
// R12 structure (proven 93.5us) with ONE change: U DMA chunks are now
// CONTIGUOUS 8-rows x 128B segments (BK=32 f32 = 128B per row per step)
// instead of 16-rows x 4 scattered 16B pieces -> 8x fewer memory segments
// per instruction. Per-row XOR swizzle ((l&7)^(l>>3)) applied to the SOURCE
// address (linear LDS dest, rule 21); the B ds_read applies the same XOR.
// Bank audit: read bank-group = 4*((2*(l>>4))^(l&7)) mod 32 -> 8 lanes/bank
// = the ds_read_b128 floor (no excess conflict).
// 256 blocks = 32 nt x 8 ks (ks = bid&7 -> one ks per XCD), 512 thr (8 waves),
// 3 buffers, distance-2, one counted vmcnt(6) + raw s_barrier per step.
__global__ __launch_bounds__(512) void gemm_kernel(const unsigned short* __restrict__ xb,
                                                   const float* __restrict__ U,
                                                   unsigned short* __restrict__ part) {
    __shared__ unsigned char lds[3][LDSBUF];

    const int tid  = threadIdx.x;
    const int lane = tid & 63;
    const int w    = tid >> 6;

    const int bid = blockIdx.x;
    const int ks  = bid & 7;
    const int nt  = bid >> 3;
    const int n0  = nt * BN;
    const int kb  = ks * KLEN;

    // --- staging chunks: c = 6w+j.
    // c<16 (A): frag c = batch rows 16c+(l&15), k-bytes (l>>4)*16 of 64B row-window.
    // c>=16 (U): cu=c-16: rows 8cu+(l>>3), contiguous 128B row-window, source
    //            byte offset 16*((l&7)^(l>>3)) (XOR pre-swizzle).
    const char* sbase[6];
    int soff[6], sstr[6];
#pragma unroll
    for (int j = 0; j < 6; ++j) {
        const int c = 6 * w + j;
        if (c < 16) {
            sbase[j] = (const char*)(xb + (long)(16 * c + (lane & 15)) * DIM
                                        + kb + (lane >> 4) * 8);
            soff[j] = c * 1024;
            sstr[j] = BK * 2;
        } else {
            const int cu = c - 16;
            sbase[j] = (const char*)(U + (long)(n0 + 8 * cu + (lane >> 3)) * DIM
                                       + kb + 4 * ((lane & 7) ^ (lane >> 3)));
            soff[j] = 16384 + cu * 1024;
            sstr[j] = BK * 4;
        }
    }

#define STAGE(TS, BUF)                                                               \
    do {                                                                             \
        _Pragma("unroll")                                                            \
        for (int j = 0; j < 6; ++j)                                                  \
            __builtin_amdgcn_global_load_lds(                                        \
                (const __attribute__((address_space(1))) void*)(sbase[j] + (long)(TS) * sstr[j]), \
                (__attribute__((address_space(3))) void*)&lds[BUF][soff[j] + lane * 16],          \
                16, 0, 0);                                                           \
    } while (0)

    // --- B read offsets (loop-invariant): for nf: chunk = 2*nfg + ((l&15)>>3),
    // slot = (l&7)*8 + (j ^ (l&7)), j0 = 2*(l>>4), j1 = j0+1.
    int rdq0[2], rdq1[2];
#pragma unroll
    for (int nf = 0; nf < 2; ++nf) {
        const int nfg = 2 * w + nf;
        const int ch  = 2 * nfg + ((lane & 15) >> 3);
        const int r   = lane & 7;
        const int j0  = 2 * (lane >> 4);
        rdq0[nf] = 16384 + ch * 1024 + (r * 8 + (j0 ^ r)) * 16;
        rdq1[nf] = 16384 + ch * 1024 + (r * 8 + ((j0 + 1) ^ r)) * 16;
    }

    f32x4 acc[16][2];
#pragma unroll
    for (int a = 0; a < 16; ++a) {
        acc[a][0] = (f32x4){0.f, 0.f, 0.f, 0.f};
        acc[a][1] = (f32x4){0.f, 0.f, 0.f, 0.f};
    }

    // ---- prologue: fill bufs 0,1; retire stage(0)
    STAGE(0, 0);
    STAGE(1, 1);
    asm volatile("s_waitcnt vmcnt(6)" ::: "memory");
    __builtin_amdgcn_s_barrier();
    asm volatile("" ::: "memory");

    for (int t = 0; t < NSTEP; ++t) {
        const int buf = t % 3;
        const int ts  = (t + 2 < NSTEP) ? t + 2 : NSTEP - 1;
        STAGE(ts, (t + 2) % 3);
        __builtin_amdgcn_sched_barrier(0);

        const char* La = (const char*)&lds[buf][0];
        const char* Lb = (const char*)&lds[buf][0];

        // B frags: swizzled ds_read_b128 pairs, f32 -> bf16 in regs
        short8 Bf[2];
#pragma unroll
        for (int nf = 0; nf < 2; ++nf) {
            f32x4 q0 = *(const f32x4*)(Lb + rdq0[nf]);
            f32x4 q1 = *(const f32x4*)(Lb + rdq1[nf]);
#pragma unroll
            for (int jj = 0; jj < 4; ++jj) {
                Bf[nf][jj]     = (short)f2b(q0[jj]);
                Bf[nf][jj + 4] = (short)f2b(q1[jj]);
            }
        }
        __builtin_amdgcn_s_setprio(1);
#pragma unroll
        for (int a = 0; a < 16; ++a) {
            short8 Af = *(const short8*)(La + a * 1024 + lane * 16);
            acc[a][0] = __builtin_amdgcn_mfma_f32_16x16x32_bf16(Af, Bf[0], acc[a][0], 0, 0, 0);
            acc[a][1] = __builtin_amdgcn_mfma_f32_16x16x32_bf16(Af, Bf[1], acc[a][1], 0, 0, 0);
        }
        __builtin_amdgcn_s_setprio(0);

        // retire stage(t+1) (keep stage(t+2)'s 6 in flight); next buf ready
        asm volatile("s_waitcnt vmcnt(6)" ::: "memory");
        __builtin_amdgcn_s_barrier();
        asm volatile("" ::: "memory");
    }
#undef STAGE

    // ---- partial store (bf16): D row=(l>>4)*4+rr -> batch, col=l&15
    unsigned short* p = part + (long)ks * (BATCH * DIM);
    const int pcol = n0 + 32 * w + (lane & 15);
#pragma unroll
    for (int a = 0; a < 16; ++a) {
        const int prow = 16 * a + (lane >> 4) * 4;
#pragma unroll
        for (int nf = 0; nf < 2; ++nf) {
#pragma unroll
            for (int rr = 0; rr < 4; ++rr)
                p[(long)(prow + rr) * DIM + pcol + nf * 16] = f2b(acc[a][nf][rr]);
        }
    }
}

// ---- reduce: out = sum of 8 bf16 partials (f32 accumulate) ----
__global__ __launch_bounds__(512) void reduce_kernel(const unsigned short* __restrict__ part,
                                                     float* __restrict__ out) {
    long i = (long)blockIdx.x * 512 + threadIdx.x;   // u16x8 index, 262144 total
    const long stride8 = (long)BATCH * DIM / 8;
    const u16x8* p = reinterpret_cast<const u16x8*>(part);
    float s[8];
#pragma unroll
    for (int j = 0; j < 8; ++j) s[j] = 0.f;
#pragma unroll
    for (int k = 0; k < KSPLIT; ++k) {
        u16x8 v = p[k * stride8 + i];
#pragma unroll
        for (int j = 0; j < 8; ++j) s[j] += b2f(v[j]);
    }
    f32x4 o0 = {s[0], s[1], s[2], s[3]};
    f32x4 o1 = {s[4], s[5], s[6], s[7]};
    reinterpret_cast<f32x4*>(out)[2 * i]     = o0;
    reinterpret_cast<f32x4*>(out)[2 * i + 1] = o1;
}

extern "C" void kernel_launch(void* const* d_in, const int* in_sizes, int n_in,
                              void* d_out, int out_size, void* d_ws, size_t ws_size,
                              hipStream_t stream) {
    const float* x = (const float*)d_in[0];     // [256, 8192] f32
    const float* U = (const float*)d_in[1];     // [8192, 8192] f32
    float* outp = (float*)d_out;                // [256, 8192] f32

    unsigned short* xb   = (unsigned short*)d_ws;                                    // 4 MB
    unsigned short* part = (unsigned short*)((char*)d_ws + (size_t)BATCH * DIM * 2); // 32 MB bf16

    cvt_x_kernel<<<(BATCH * DIM / 4) / 512, 512, 0, stream>>>(x, xb);
    gemm_kernel<<<NTILE * KSPLIT, 512, 0, stream>>>(xb, U, part);
    reduce_kernel<<<(BATCH * DIM / 8) / 512, 512, 0, stream>>>(part, outp);
}